// Round 6
// baseline (7049.633 us; speedup 1.0000x reference)
//
#include <hip/hip_runtime.h>
#include <stdint.h>
#include <stddef.h>

typedef __bf16 bf16;
typedef bf16 bf16x8 __attribute__((ext_vector_type(8)));
typedef bf16 bf16x4 __attribute__((ext_vector_type(4)));
typedef float f32x4 __attribute__((ext_vector_type(4)));

#define B_   16
#define CI   192
#define CO   192
#define H_   128
#define W_   128
#define KE   8
#define LD   64
#define KTOT 1728   // 9*192
#define HP   130    // padded H/W
#define HPHP (HP*HP)
#define NPX  (H_*W_)
#define NT   54     // K micro-steps of 32 (order: r-major, ib, s-minor)

__device__ __forceinline__ void gll16(const void* g, void* l) {
  __builtin_amdgcn_global_load_lds(
      (const __attribute__((address_space(1))) unsigned int*)g,
      (__attribute__((address_space(3))) unsigned int*)l, 16, 0, 0);
}

__device__ __forceinline__ float silu_f(float x) {
  return x / (1.f + __expf(-x));
}

// ---------------- attention softmax: latent[16,64] -> attn[16,8] ----------------
__global__ void k_attn(const float* __restrict__ latent, const float* __restrict__ attn_w,
                       const float* __restrict__ attn_b, float* __restrict__ attn) {
  int t = threadIdx.x;           // 128 threads: b = t>>3, k = t&7
  int b = t >> 3, k = t & 7;
  float s = attn_b[k];
  for (int d = 0; d < LD; ++d) s += latent[b*LD + d] * attn_w[k*LD + d];
  float m = s;
  for (int off = 4; off; off >>= 1) m = fmaxf(m, __shfl_xor(m, off, 8));
  float e = __expf(s - m);
  float sum = e;
  for (int off = 4; off; off >>= 1) sum += __shfl_xor(sum, off, 8);
  attn[t] = e / sum;
}

// ---------------- dynamic bias ----------------
__global__ void k_bdyn(const float* __restrict__ attn, const float* __restrict__ expert_b,
                       float* __restrict__ bdyn) {
  int j = blockIdx.x * 256 + threadIdx.x;
  if (j >= B_ * CO) return;
  int b = j / CO, o = j - b * CO;
  float s = 0.f;
  #pragma unroll
  for (int e = 0; e < KE; ++e) s += attn[b*KE + e] * expert_b[e*CO + o];
  bdyn[j] = s;
}

// ---------------- dynamic weights -> staged layout [b][kt=54][chunk=12][slot=64][8] bf16
// K order: kt = r*18 + ib*3 + s  (s innermost). slot L holds (row=L>>2, ks=(L&3)^((row>>1)&3)).
// element: o = chunk*16+row, i = ib*32 + ks*8 + j, weight (o, i, r, s).
__global__ void k_wdyn(const float* __restrict__ expert_w, const float* __restrict__ attn,
                       bf16* __restrict__ w_re) {
  int o = blockIdx.x;            // 192
  int chunk = o >> 4, row = o & 15, c = (row >> 1) & 3;
  __shared__ float ew[KE][KTOT];
  __shared__ float al[B_][KE];
  for (int e = 0; e < KE; ++e)
    for (int j = threadIdx.x; j < KTOT; j += 256)
      ew[e][j] = expert_w[((size_t)e*CO + o)*KTOT + j];   // [i*9+rs]
  if (threadIdx.x < B_*KE) al[threadIdx.x >> 3][threadIdx.x & 7] = attn[threadIdx.x];
  __syncthreads();
  for (int idx = threadIdx.x; idx < B_*KTOT; idx += 256) {
    int b = idx / KTOT, k = idx - b*KTOT;
    int kt = k >> 5, ks = (k >> 3) & 3, j = k & 7;
    int r = kt / 18, t2 = kt - r*18;
    int ibb = t2 / 3, s = t2 - ibb*3;
    int i = ibb*32 + ks*8 + j;
    float acc = 0.f;
    #pragma unroll
    for (int e = 0; e < KE; ++e) acc += al[b][e] * ew[e][i*9 + r*3 + s];
    int slot = row*4 + (ks ^ c);
    w_re[((((size_t)b*NT + kt)*12 + chunk)*64 + slot)*8 + j] = (bf16)acc;
  }
}

// ---------------- static conv2 weights -> same staged layout (no b) ----------------
__global__ void k_w2re(const float* __restrict__ conv2_w, bf16* __restrict__ w2_re) {
  int o = blockIdx.x;
  int chunk = o >> 4, row = o & 15, c = (row >> 1) & 3;
  __shared__ float cw[KTOT];
  for (int j = threadIdx.x; j < KTOT; j += 256) cw[j] = conv2_w[(size_t)o*KTOT + j];
  __syncthreads();
  for (int k = threadIdx.x; k < KTOT; k += 256) {
    int kt = k >> 5, ks = (k >> 3) & 3, j = k & 7;
    int r = kt / 18, t2 = kt - r*18;
    int ibb = t2 / 3, s = t2 - ibb*3;
    int i = ibb*32 + ks*8 + j;
    int slot = row*4 + (ks ^ c);
    w2_re[(((size_t)kt*12 + chunk)*64 + slot)*8 + j] = (bf16)cw[i*9 + r*3 + s];
  }
}

// ---------------- pack+pad x: f32 NCHW -> bf16 [b][i/8][130][130][8], zero borders ----------------
__global__ void k_xpack(const float* __restrict__ x, bf16* __restrict__ xpack) {
  int h2 = blockIdx.x, ib = blockIdx.y, b = blockIdx.z;
  size_t rowbase = (((size_t)b*24 + ib)*HP + h2)*HP;
  int t = threadIdx.x;  // 128
  if (h2 == 0 || h2 == HP-1) {
    uint4 z = make_uint4(0,0,0,0);
    for (int w = t; w < HP; w += 128) *(uint4*)(xpack + (rowbase + w)*8) = z;
    return;
  }
  __shared__ float tt[8][128];
  int h = h2 - 1;
  #pragma unroll
  for (int ii = 0; ii < 8; ++ii)
    tt[ii][t] = x[(((size_t)b*CI + ib*8 + ii)*H_ + h)*W_ + t];
  __syncthreads();
  bf16x8 v;
  #pragma unroll
  for (int ii = 0; ii < 8; ++ii) v[ii] = (bf16)tt[ii][t];
  *(bf16x8*)(xpack + (rowbase + t + 1)*8) = v;
  if (t == 0) {
    uint4 z = make_uint4(0,0,0,0);
    *(uint4*)(xpack + rowbase*8) = z;
    *(uint4*)(xpack + (rowbase + HP-1)*8) = z;
  }
}

// ---------------- zero borders of midpack ----------------
__global__ void k_midborder(bf16* __restrict__ midpack) {
  int bi = blockIdx.x;  // b*24+ib
  size_t base = (size_t)bi * HPHP;
  uint4 z = make_uint4(0,0,0,0);
  for (int j = threadIdx.x; j < 516; j += 256) {
    int h2, w2;
    if (j < 130)      { h2 = 0;       w2 = j; }
    else if (j < 260) { h2 = 129;     w2 = j - 130; }
    else if (j < 388) { h2 = j - 259; w2 = 0; }
    else              { h2 = j - 387; w2 = 129; }
    *(uint4*)(midpack + (base + (size_t)h2*HP + w2)*8) = z;
  }
}

// ---------------- implicit-GEMM 3x3 conv, BM=192 x BN=128(1 row), K order (r,ib,s) ----------
// 2 waves per block (wm = o-half), per-wave 96x128. 18 macros (r,ib) x 3 micros (s).
// A: loaded per-wave straight from L2 into registers (ping-pong sets, 1 micro ahead).
// B: one row x 4 ch-groups staged per macro into LDS (2 buffers, staged 1 macro ahead);
//    s served by +16B shift on the ds_read. ONE barrier + one manual vmcnt(6) per macro.
// FIFO invariant at macro entry: [B(m) 6 gll16, af(s0) 6 reg-loads] -> vmcnt(6) lands B(m).
template<int MODE>
__global__ __launch_bounds__(128, 4)
void k_conv(const bf16* __restrict__ wre, const bf16* __restrict__ inpack,
            const float* __restrict__ bias_g, const bf16* __restrict__ respack,
            bf16* __restrict__ outpack, float* __restrict__ outp) {
  const int tid  = threadIdx.x;
  const int lane = tid & 63;
  const int wm   = tid >> 6;          // 0..1 (o half)
  const int l15  = lane & 15, l4 = lane >> 4;

  // XCD-aware chunked remap: 2048 blocks, 256/XCD => each XCD owns 2 batches
  const int bid  = blockIdx.x;
  const int n    = (bid & 7) * 256 + (bid >> 3);
  const int b    = n >> 7;
  const int row  = n & 127;
  const int p0   = row * 128;

  __shared__ __align__(16) bf16 Blds[2][4*1152];   // 18432 B
  __shared__ float bias_lds[CO];

  for (int j = tid; j < CO; j += 128)
    bias_lds[j] = (MODE == 0) ? bias_g[b*CO + j] : bias_g[j];

  const size_t wbase = (MODE == 0) ? ((size_t)b*CO*KTOT) : 0;

  // A: per-lane global pointer, +6144 el per micro; sw un-swizzles the baked LDS swizzle
  const int sw = l15*4 + (l4 ^ ((l15 >> 1) & 3));
  const bf16* aptr = wre + wbase + (size_t)(wm*6)*512 + (size_t)sw*8;

  // B staging: wave wm stages kg pair {2wm, 2wm+1}; row r of macro; 3 overlapped 1KB chunks/kg
  const bf16* bsrc0 = inpack + (((size_t)b*24 + wm*2    )*HPHP + (size_t)row*HP)*8 + lane*8;
  const bf16* bsrc1 = inpack + (((size_t)b*24 + wm*2 + 1)*HPHP + (size_t)row*HP)*8 + lane*8;
  ptrdiff_t boff = 0; int ibm = 0;

  auto stageB = [&](bf16* dbuf) {
    const bf16* s0 = bsrc0 + boff;
    const bf16* s1 = bsrc1 + boff;
    bf16* d0 = dbuf + (wm*2)*1152;
    bf16* d1 = d0 + 1152;
    gll16(s0,       d0);
    gll16(s0 + 512, d0 + 512);
    gll16(s0 + 528, d0 + 528);   // covers el 528..1040 (overlap benign, same data)
    gll16(s1,       d1);
    gll16(s1 + 512, d1 + 512);
    gll16(s1 + 528, d1 + 528);
    if (++ibm == 6) { ibm = 0; boff += (ptrdiff_t)(HP - 20*HPHP)*8; }
    else boff += (ptrdiff_t)4*HPHP*8;
  };

  bf16x8 afA[6], afB[6];
  auto loadA = [&](bf16x8* s) {
    #pragma unroll
    for (int mf = 0; mf < 6; ++mf) s[mf] = *(const bf16x8*)(aptr + mf*512);
    aptr += 6144;
  };

  f32x4 acc[6][8];
  #pragma unroll
  for (int mf = 0; mf < 6; ++mf)
    #pragma unroll
    for (int nf = 0; nf < 8; ++nf)
      #pragma unroll
      for (int jj = 0; jj < 4; ++jj) acc[mf][nf][jj] = 0.f;

  auto MICRO = [&](const bf16x8* af, const bf16* Bc, int s) {
    const bf16* bp = Bc + l4*1152 + (l15 + s)*8;
    __builtin_amdgcn_s_setprio(1);
    #pragma unroll
    for (int nf = 0; nf < 8; ++nf) {
      bf16x8 bv = *(const bf16x8*)(bp + nf*128);
      acc[0][nf] = __builtin_amdgcn_mfma_f32_16x16x32_bf16(af[0], bv, acc[0][nf], 0, 0, 0);
      acc[1][nf] = __builtin_amdgcn_mfma_f32_16x16x32_bf16(af[1], bv, acc[1][nf], 0, 0, 0);
      acc[2][nf] = __builtin_amdgcn_mfma_f32_16x16x32_bf16(af[2], bv, acc[2][nf], 0, 0, 0);
      acc[3][nf] = __builtin_amdgcn_mfma_f32_16x16x32_bf16(af[3], bv, acc[3][nf], 0, 0, 0);
      acc[4][nf] = __builtin_amdgcn_mfma_f32_16x16x32_bf16(af[4], bv, acc[4][nf], 0, 0, 0);
      acc[5][nf] = __builtin_amdgcn_mfma_f32_16x16x32_bf16(af[5], bv, acc[5][nf], 0, 0, 0);
    }
    __builtin_amdgcn_s_setprio(0);
  };

  // prologue: B(0) first (FIFO oldest), then af(u=0)
  stageB((bf16*)Blds[0]);
  loadA(afA);

  for (int mm = 0; mm < 9; ++mm) {
    // ---- macro 2mm (even): B buffer 0 ----
    asm volatile("s_waitcnt vmcnt(6)" ::: "memory");
    __builtin_amdgcn_s_barrier();
    loadA(afB);                       // af(s1)
    MICRO(afA, (const bf16*)Blds[0], 0);
    loadA(afA);                       // af(s2)  (issued BEFORE next B-stage: FIFO)
    stageB((bf16*)Blds[1]);           // B(2mm+1)
    MICRO(afB, (const bf16*)Blds[0], 1);
    loadA(afB);                       // af(s0 of 2mm+1)
    MICRO(afA, (const bf16*)Blds[0], 2);

    // ---- macro 2mm+1 (odd): B buffer 1 ----
    asm volatile("s_waitcnt vmcnt(6)" ::: "memory");
    __builtin_amdgcn_s_barrier();
    loadA(afA);                       // af(s1)
    MICRO(afB, (const bf16*)Blds[1], 0);
    loadA(afB);                       // af(s2)
    if (mm < 8) stageB((bf16*)Blds[0]);   // B(2mm+2); skip past-end stage at m=17
    MICRO(afA, (const bf16*)Blds[1], 1);
    loadA(afA);                       // af(s0 of next even macro) — harmless overrun at end
    MICRO(afB, (const bf16*)Blds[1], 2);
  }

  // epilogue
  #pragma unroll
  for (int mf = 0; mf < 6; ++mf) {
    int ob = wm*96 + mf*16 + l4*4;     // output channel base (4 consecutive)
    #pragma unroll
    for (int nf = 0; nf < 8; ++nf) {
      int pl = nf*16 + l15;
      int p  = p0 + pl;
      f32x4 v = acc[mf][nf];
      size_t basep = (((size_t)b*24 + (ob >> 3))*HP + (row + 1))*HP + (pl + 1);
      if (MODE == 0) {
        bf16x4 pk;
        #pragma unroll
        for (int jj = 0; jj < 4; ++jj) {
          float xv = v[jj] + bias_lds[ob + jj];
          pk[jj] = (bf16)silu_f(xv);
        }
        *(bf16x4*)(outpack + basep*8 + (ob & 7)) = pk;
      } else {
        bf16x4 rr = *(const bf16x4*)(respack + basep*8 + (ob & 7));
        #pragma unroll
        for (int jj = 0; jj < 4; ++jj) {
          float xv = silu_f(v[jj] + bias_lds[ob + jj]);
          size_t idx = ((size_t)b*CO + ob + jj)*NPX + p;
          outp[idx] = xv + (float)rr[jj];
        }
      }
    }
  }
}

extern "C" void kernel_launch(void* const* d_in, const int* in_sizes, int n_in,
                              void* d_out, int out_size, void* d_ws, size_t ws_size,
                              hipStream_t stream) {
  const float* x        = (const float*)d_in[0];
  const float* latent   = (const float*)d_in[1];
  const float* expert_w = (const float*)d_in[2];
  const float* expert_b = (const float*)d_in[3];
  const float* attn_w   = (const float*)d_in[4];
  const float* attn_b   = (const float*)d_in[5];
  const float* conv2_w  = (const float*)d_in[6];
  const float* conv2_b  = (const float*)d_in[7];
  float* outp = (float*)d_out;

  char* base = (char*)d_ws;
  size_t off = 0;
  float* attn = (float*)(base + off); off += 4096;
  float* bdyn = (float*)(base + off); off += 16384;
  bf16* w_re  = (bf16*)(base + off);  off += (size_t)B_*CO*KTOT*2;      // 10.6 MB
  bf16* w2_re = (bf16*)(base + off);  off += (size_t)CO*KTOT*2;         // 0.66 MB
  bf16* xpack = (bf16*)(base + off);  off += (size_t)B_*24*HPHP*8*2;    // 103.8 MB
  bf16* midpack = (bf16*)(base + off); off += (size_t)B_*24*HPHP*8*2;   // 103.8 MB
  (void)ws_size; (void)in_sizes; (void)n_in; (void)out_size;

  k_attn<<<dim3(1), dim3(128), 0, stream>>>(latent, attn_w, attn_b, attn);
  k_bdyn<<<dim3(12), dim3(256), 0, stream>>>(attn, expert_b, bdyn);
  k_wdyn<<<dim3(CO), dim3(256), 0, stream>>>(expert_w, attn, w_re);
  k_w2re<<<dim3(CO), dim3(256), 0, stream>>>(conv2_w, w2_re);
  k_xpack<<<dim3(130, 24, 16), dim3(128), 0, stream>>>(x, xpack);
  k_midborder<<<dim3(B_*24), dim3(256), 0, stream>>>(midpack);
  k_conv<0><<<dim3(2048), dim3(128), 0, stream>>>(w_re, xpack, bdyn, xpack, midpack, outp);
  k_conv<1><<<dim3(2048), dim3(128), 0, stream>>>(w2_re, midpack, conv2_b, xpack, midpack, outp);
}

// Round 7
// 1869.692 us; speedup vs baseline: 3.7705x; 3.7705x over previous
//
#include <hip/hip_runtime.h>
#include <stdint.h>
#include <stddef.h>

typedef __bf16 bf16;
typedef bf16 bf16x8 __attribute__((ext_vector_type(8)));
typedef bf16 bf16x4 __attribute__((ext_vector_type(4)));
typedef float f32x4 __attribute__((ext_vector_type(4)));

#define B_   16
#define CI   192
#define CO   192
#define H_   128
#define W_   128
#define KE   8
#define LD   64
#define KTOT 1728   // 9*192
#define HP   130    // padded H/W
#define HPHP (HP*HP)
#define NPX  (H_*W_)
#define NT   54     // K micro-steps of 32 (order: r-major, ib, s-minor)

__device__ __forceinline__ void gll16(const void* g, void* l) {
  __builtin_amdgcn_global_load_lds(
      (const __attribute__((address_space(1))) unsigned int*)g,
      (__attribute__((address_space(3))) unsigned int*)l, 16, 0, 0);
}

__device__ __forceinline__ float silu_f(float x) {
  return x / (1.f + __expf(-x));
}

// ---------------- attention softmax: latent[16,64] -> attn[16,8] ----------------
__global__ void k_attn(const float* __restrict__ latent, const float* __restrict__ attn_w,
                       const float* __restrict__ attn_b, float* __restrict__ attn) {
  int t = threadIdx.x;           // 128 threads: b = t>>3, k = t&7
  int b = t >> 3, k = t & 7;
  float s = attn_b[k];
  for (int d = 0; d < LD; ++d) s += latent[b*LD + d] * attn_w[k*LD + d];
  float m = s;
  for (int off = 4; off; off >>= 1) m = fmaxf(m, __shfl_xor(m, off, 8));
  float e = __expf(s - m);
  float sum = e;
  for (int off = 4; off; off >>= 1) sum += __shfl_xor(sum, off, 8);
  attn[t] = e / sum;
}

// ---------------- dynamic bias ----------------
__global__ void k_bdyn(const float* __restrict__ attn, const float* __restrict__ expert_b,
                       float* __restrict__ bdyn) {
  int j = blockIdx.x * 256 + threadIdx.x;
  if (j >= B_ * CO) return;
  int b = j / CO, o = j - b * CO;
  float s = 0.f;
  #pragma unroll
  for (int e = 0; e < KE; ++e) s += attn[b*KE + e] * expert_b[e*CO + o];
  bdyn[j] = s;
}

// ---------------- dynamic weights -> staged layout [b][kt=54][chunk=12][slot=64][8] bf16
// K order: kt = r*18 + ib*3 + s  (s innermost). slot L holds (row=L>>2, ks=(L&3)^((row>>1)&3)).
// element: o = chunk*16+row, i = ib*32 + ks*8 + j, weight (o, i, r, s).
__global__ void k_wdyn(const float* __restrict__ expert_w, const float* __restrict__ attn,
                       bf16* __restrict__ w_re) {
  int o = blockIdx.x;            // 192
  int chunk = o >> 4, row = o & 15, c = (row >> 1) & 3;
  __shared__ float ew[KE][KTOT];
  __shared__ float al[B_][KE];
  for (int e = 0; e < KE; ++e)
    for (int j = threadIdx.x; j < KTOT; j += 256)
      ew[e][j] = expert_w[((size_t)e*CO + o)*KTOT + j];   // [i*9+rs]
  if (threadIdx.x < B_*KE) al[threadIdx.x >> 3][threadIdx.x & 7] = attn[threadIdx.x];
  __syncthreads();
  for (int idx = threadIdx.x; idx < B_*KTOT; idx += 256) {
    int b = idx / KTOT, k = idx - b*KTOT;
    int kt = k >> 5, ks = (k >> 3) & 3, j = k & 7;
    int r = kt / 18, t2 = kt - r*18;
    int ibb = t2 / 3, s = t2 - ibb*3;
    int i = ibb*32 + ks*8 + j;
    float acc = 0.f;
    #pragma unroll
    for (int e = 0; e < KE; ++e) acc += al[b][e] * ew[e][i*9 + r*3 + s];
    int slot = row*4 + (ks ^ c);
    w_re[((((size_t)b*NT + kt)*12 + chunk)*64 + slot)*8 + j] = (bf16)acc;
  }
}

// ---------------- static conv2 weights -> same staged layout (no b) ----------------
__global__ void k_w2re(const float* __restrict__ conv2_w, bf16* __restrict__ w2_re) {
  int o = blockIdx.x;
  int chunk = o >> 4, row = o & 15, c = (row >> 1) & 3;
  __shared__ float cw[KTOT];
  for (int j = threadIdx.x; j < KTOT; j += 256) cw[j] = conv2_w[(size_t)o*KTOT + j];
  __syncthreads();
  for (int k = threadIdx.x; k < KTOT; k += 256) {
    int kt = k >> 5, ks = (k >> 3) & 3, j = k & 7;
    int r = kt / 18, t2 = kt - r*18;
    int ibb = t2 / 3, s = t2 - ibb*3;
    int i = ibb*32 + ks*8 + j;
    int slot = row*4 + (ks ^ c);
    w2_re[(((size_t)kt*12 + chunk)*64 + slot)*8 + j] = (bf16)cw[i*9 + r*3 + s];
  }
}

// ---------------- pack+pad x: f32 NCHW -> bf16 [b][i/8][130][130][8], zero borders ----------------
__global__ void k_xpack(const float* __restrict__ x, bf16* __restrict__ xpack) {
  int h2 = blockIdx.x, ib = blockIdx.y, b = blockIdx.z;
  size_t rowbase = (((size_t)b*24 + ib)*HP + h2)*HP;
  int t = threadIdx.x;  // 128
  if (h2 == 0 || h2 == HP-1) {
    uint4 z = make_uint4(0,0,0,0);
    for (int w = t; w < HP; w += 128) *(uint4*)(xpack + (rowbase + w)*8) = z;
    return;
  }
  __shared__ float tt[8][128];
  int h = h2 - 1;
  #pragma unroll
  for (int ii = 0; ii < 8; ++ii)
    tt[ii][t] = x[(((size_t)b*CI + ib*8 + ii)*H_ + h)*W_ + t];
  __syncthreads();
  bf16x8 v;
  #pragma unroll
  for (int ii = 0; ii < 8; ++ii) v[ii] = (bf16)tt[ii][t];
  *(bf16x8*)(xpack + (rowbase + t + 1)*8) = v;
  if (t == 0) {
    uint4 z = make_uint4(0,0,0,0);
    *(uint4*)(xpack + rowbase*8) = z;
    *(uint4*)(xpack + (rowbase + HP-1)*8) = z;
  }
}

// ---------------- zero borders of midpack ----------------
__global__ void k_midborder(bf16* __restrict__ midpack) {
  int bi = blockIdx.x;  // b*24+ib
  size_t base = (size_t)bi * HPHP;
  uint4 z = make_uint4(0,0,0,0);
  for (int j = threadIdx.x; j < 516; j += 256) {
    int h2, w2;
    if (j < 130)      { h2 = 0;       w2 = j; }
    else if (j < 260) { h2 = 129;     w2 = j - 130; }
    else if (j < 388) { h2 = j - 259; w2 = 0; }
    else              { h2 = j - 387; w2 = 129; }
    *(uint4*)(midpack + (base + (size_t)h2*HP + w2)*8) = z;
  }
}

// ---------------- implicit-GEMM 3x3 conv, BM=192 x BN=128(1 row), K order (r,ib,s) ----------
// 2 waves per block (wm = o-half), per-wave 96x128. 18 macros (r,ib) x 3 micros (s).
// A: straight from L2 into NAMED register fragments (ping-pong sets via macros — no
//    arrays-through-pointers; R6's scratch-spill fix). B: one row x 4 ch-groups staged per
//    macro into LDS (2 buffers, 1 macro ahead); s served by +16B shift on the ds_read.
// ONE barrier + one manual vmcnt(6) per macro. Pure 48-MFMA clusters:
//    8x ds_read_b128 -> lgkmcnt(0) + sched_barrier -> setprio(1) 48 MFMA setprio(0).
#define LOADA(p0,p1,p2,p3,p4,p5) do {            \
    p0 = *(const bf16x8*)(aptr);                 \
    p1 = *(const bf16x8*)(aptr +  512);          \
    p2 = *(const bf16x8*)(aptr + 1024);          \
    p3 = *(const bf16x8*)(aptr + 1536);          \
    p4 = *(const bf16x8*)(aptr + 2048);          \
    p5 = *(const bf16x8*)(aptr + 2560);          \
    aptr += 6144;                                \
  } while (0)

#define MICRO(q0,q1,q2,q3,q4,q5, Bc, s) do {                                           \
    const bf16* bp_ = (Bc) + l4*1152 + (l15 + (s))*8;                                  \
    bf16x8 bv[8];                                                                      \
    _Pragma("unroll")                                                                  \
    for (int nf = 0; nf < 8; ++nf) bv[nf] = *(const bf16x8*)(bp_ + nf*128);            \
    asm volatile("s_waitcnt lgkmcnt(0)" ::: "memory");                                 \
    __builtin_amdgcn_sched_barrier(0);                                                 \
    __builtin_amdgcn_s_setprio(1);                                                     \
    _Pragma("unroll")                                                                  \
    for (int nf = 0; nf < 8; ++nf) {                                                   \
      acc[0][nf] = __builtin_amdgcn_mfma_f32_16x16x32_bf16(q0, bv[nf], acc[0][nf],0,0,0); \
      acc[1][nf] = __builtin_amdgcn_mfma_f32_16x16x32_bf16(q1, bv[nf], acc[1][nf],0,0,0); \
      acc[2][nf] = __builtin_amdgcn_mfma_f32_16x16x32_bf16(q2, bv[nf], acc[2][nf],0,0,0); \
      acc[3][nf] = __builtin_amdgcn_mfma_f32_16x16x32_bf16(q3, bv[nf], acc[3][nf],0,0,0); \
      acc[4][nf] = __builtin_amdgcn_mfma_f32_16x16x32_bf16(q4, bv[nf], acc[4][nf],0,0,0); \
      acc[5][nf] = __builtin_amdgcn_mfma_f32_16x16x32_bf16(q5, bv[nf], acc[5][nf],0,0,0); \
    }                                                                                  \
    __builtin_amdgcn_s_setprio(0);                                                     \
    __builtin_amdgcn_sched_barrier(0);                                                 \
  } while (0)

template<int MODE>
__global__ __launch_bounds__(128, 2)
void k_conv(const bf16* __restrict__ wre, const bf16* __restrict__ inpack,
            const float* __restrict__ bias_g, const bf16* __restrict__ respack,
            bf16* __restrict__ outpack, float* __restrict__ outp) {
  const int tid  = threadIdx.x;
  const int lane = tid & 63;
  const int wm   = tid >> 6;          // 0..1 (o half)
  const int l15  = lane & 15, l4 = lane >> 4;

  // XCD-aware chunked remap: 2048 blocks, 256/XCD => each XCD owns 2 batches
  const int bid  = blockIdx.x;
  const int n    = (bid & 7) * 256 + (bid >> 3);
  const int b    = n >> 7;
  const int row  = n & 127;
  const int p0   = row * 128;

  __shared__ __align__(16) bf16 Blds[2][4*1152];   // 18432 B
  __shared__ float bias_lds[CO];

  for (int j = tid; j < CO; j += 128)
    bias_lds[j] = (MODE == 0) ? bias_g[b*CO + j] : bias_g[j];

  const size_t wbase = (MODE == 0) ? ((size_t)b*CO*KTOT) : 0;

  // A: per-lane global pointer, +6144 el per micro; sw un-swizzles the baked LDS swizzle
  const int sw = l15*4 + (l4 ^ ((l15 >> 1) & 3));
  const bf16* aptr = wre + wbase + (size_t)(wm*6)*512 + (size_t)sw*8;

  // B staging: wave wm stages kg pair {2wm, 2wm+1}; row of macro; 3 overlapped 1KB chunks/kg
  const bf16* bsrc0 = inpack + (((size_t)b*24 + wm*2    )*HPHP + (size_t)row*HP)*8 + lane*8;
  const bf16* bsrc1 = inpack + (((size_t)b*24 + wm*2 + 1)*HPHP + (size_t)row*HP)*8 + lane*8;
  ptrdiff_t boff = 0; int ibm = 0;

  auto stageB = [&](bf16* dbuf) {
    const bf16* s0 = bsrc0 + boff;
    const bf16* s1 = bsrc1 + boff;
    bf16* d0 = dbuf + (wm*2)*1152;
    bf16* d1 = d0 + 1152;
    gll16(s0,       d0);
    gll16(s0 + 512, d0 + 512);
    gll16(s0 + 528, d0 + 528);   // covers el 528..1040 (overlap benign, same data)
    gll16(s1,       d1);
    gll16(s1 + 512, d1 + 512);
    gll16(s1 + 528, d1 + 528);
    if (++ibm == 6) { ibm = 0; boff += (ptrdiff_t)(HP - 20*HPHP)*8; }
    else boff += (ptrdiff_t)4*HPHP*8;
  };

  f32x4 acc[6][8];
  #pragma unroll
  for (int mf = 0; mf < 6; ++mf)
    #pragma unroll
    for (int nf = 0; nf < 8; ++nf)
      #pragma unroll
      for (int jj = 0; jj < 4; ++jj) acc[mf][nf][jj] = 0.f;

  bf16x8 a0, a1, a2, a3, a4, a5;      // fragment set A (named: stays in VGPRs)
  bf16x8 g0, g1, g2, g3, g4, g5;      // fragment set B

  // prologue: B(0) first (FIFO oldest), then af(u=0)
  stageB((bf16*)Blds[0]);
  LOADA(a0,a1,a2,a3,a4,a5);

  for (int mm = 0; mm < 9; ++mm) {
    // ---- macro 2mm (even): B buffer 0 ----
    asm volatile("s_waitcnt vmcnt(6)" ::: "memory");
    __builtin_amdgcn_s_barrier();
    LOADA(g0,g1,g2,g3,g4,g5);                    // af(s1)
    MICRO(a0,a1,a2,a3,a4,a5, (const bf16*)Blds[0], 0);
    LOADA(a0,a1,a2,a3,a4,a5);                    // af(s2)  (issued BEFORE next B-stage: FIFO)
    stageB((bf16*)Blds[1]);                      // B(2mm+1)
    MICRO(g0,g1,g2,g3,g4,g5, (const bf16*)Blds[0], 1);
    LOADA(g0,g1,g2,g3,g4,g5);                    // af(s0 of 2mm+1)
    MICRO(a0,a1,a2,a3,a4,a5, (const bf16*)Blds[0], 2);

    // ---- macro 2mm+1 (odd): B buffer 1 ----
    asm volatile("s_waitcnt vmcnt(6)" ::: "memory");
    __builtin_amdgcn_s_barrier();
    LOADA(a0,a1,a2,a3,a4,a5);                    // af(s1)
    MICRO(g0,g1,g2,g3,g4,g5, (const bf16*)Blds[1], 0);
    LOADA(g0,g1,g2,g3,g4,g5);                    // af(s2)
    if (mm < 8) stageB((bf16*)Blds[0]);          // B(2mm+2); skip past-end stage at m=17
    MICRO(a0,a1,a2,a3,a4,a5, (const bf16*)Blds[1], 1);
    LOADA(a0,a1,a2,a3,a4,a5);                    // af(s0 of next even) — harmless overrun at end
    MICRO(g0,g1,g2,g3,g4,g5, (const bf16*)Blds[1], 2);
  }

  // epilogue
  #pragma unroll
  for (int mf = 0; mf < 6; ++mf) {
    int ob = wm*96 + mf*16 + l4*4;     // output channel base (4 consecutive)
    #pragma unroll
    for (int nf = 0; nf < 8; ++nf) {
      int pl = nf*16 + l15;
      int p  = p0 + pl;
      f32x4 v = acc[mf][nf];
      size_t basep = (((size_t)b*24 + (ob >> 3))*HP + (row + 1))*HP + (pl + 1);
      if (MODE == 0) {
        bf16x4 pk;
        #pragma unroll
        for (int jj = 0; jj < 4; ++jj) {
          float xv = v[jj] + bias_lds[ob + jj];
          pk[jj] = (bf16)silu_f(xv);
        }
        *(bf16x4*)(outpack + basep*8 + (ob & 7)) = pk;
      } else {
        bf16x4 rr = *(const bf16x4*)(respack + basep*8 + (ob & 7));
        #pragma unroll
        for (int jj = 0; jj < 4; ++jj) {
          float xv = silu_f(v[jj] + bias_lds[ob + jj]);
          size_t idx = ((size_t)b*CO + ob + jj)*NPX + p;
          outp[idx] = xv + (float)rr[jj];
        }
      }
    }
  }
}

extern "C" void kernel_launch(void* const* d_in, const int* in_sizes, int n_in,
                              void* d_out, int out_size, void* d_ws, size_t ws_size,
                              hipStream_t stream) {
  const float* x        = (const float*)d_in[0];
  const float* latent   = (const float*)d_in[1];
  const float* expert_w = (const float*)d_in[2];
  const float* expert_b = (const float*)d_in[3];
  const float* attn_w   = (const float*)d_in[4];
  const float* attn_b   = (const float*)d_in[5];
  const float* conv2_w  = (const float*)d_in[6];
  const float* conv2_b  = (const float*)d_in[7];
  float* outp = (float*)d_out;

  char* base = (char*)d_ws;
  size_t off = 0;
  float* attn = (float*)(base + off); off += 4096;
  float* bdyn = (float*)(base + off); off += 16384;
  bf16* w_re  = (bf16*)(base + off);  off += (size_t)B_*CO*KTOT*2;      // 10.6 MB
  bf16* w2_re = (bf16*)(base + off);  off += (size_t)CO*KTOT*2;         // 0.66 MB
  bf16* xpack = (bf16*)(base + off);  off += (size_t)B_*24*HPHP*8*2;    // 103.8 MB
  bf16* midpack = (bf16*)(base + off); off += (size_t)B_*24*HPHP*8*2;   // 103.8 MB
  (void)ws_size; (void)in_sizes; (void)n_in; (void)out_size;

  k_attn<<<dim3(1), dim3(128), 0, stream>>>(latent, attn_w, attn_b, attn);
  k_bdyn<<<dim3(12), dim3(256), 0, stream>>>(attn, expert_b, bdyn);
  k_wdyn<<<dim3(CO), dim3(256), 0, stream>>>(expert_w, attn, w_re);
  k_w2re<<<dim3(CO), dim3(256), 0, stream>>>(conv2_w, w2_re);
  k_xpack<<<dim3(130, 24, 16), dim3(128), 0, stream>>>(x, xpack);
  k_midborder<<<dim3(B_*24), dim3(256), 0, stream>>>(midpack);
  k_conv<0><<<dim3(2048), dim3(128), 0, stream>>>(w_re, xpack, bdyn, xpack, midpack, outp);
  k_conv<1><<<dim3(2048), dim3(128), 0, stream>>>(w2_re, midpack, conv2_b, xpack, midpack, outp);
}

// Round 8
// 483.503 us; speedup vs baseline: 14.5803x; 3.8670x over previous
//
#include <hip/hip_runtime.h>
#include <stdint.h>
#include <stddef.h>

typedef __bf16 bf16;
typedef bf16 bf16x8 __attribute__((ext_vector_type(8)));
typedef bf16 bf16x4 __attribute__((ext_vector_type(4)));
typedef float f32x4 __attribute__((ext_vector_type(4)));

#define B_   16
#define CI   192
#define CO   192
#define H_   128
#define W_   128
#define KE   8
#define LD   64
#define KTOT 1728   // 9*192
#define HP   130    // padded H/W
#define HPHP (HP*HP)
#define NPX  (H_*W_)
#define NT   54     // K micro-steps of 32 (order: r-major, ib, s-minor)

__device__ __forceinline__ void gll16(const void* g, void* l) {
  __builtin_amdgcn_global_load_lds(
      (const __attribute__((address_space(1))) unsigned int*)g,
      (__attribute__((address_space(3))) unsigned int*)l, 16, 0, 0);
}

__device__ __forceinline__ float silu_f(float x) {
  return x / (1.f + __expf(-x));
}

// ---------------- attention softmax: latent[16,64] -> attn[16,8] ----------------
__global__ void k_attn(const float* __restrict__ latent, const float* __restrict__ attn_w,
                       const float* __restrict__ attn_b, float* __restrict__ attn) {
  int t = threadIdx.x;           // 128 threads: b = t>>3, k = t&7
  int b = t >> 3, k = t & 7;
  float s = attn_b[k];
  for (int d = 0; d < LD; ++d) s += latent[b*LD + d] * attn_w[k*LD + d];
  float m = s;
  for (int off = 4; off; off >>= 1) m = fmaxf(m, __shfl_xor(m, off, 8));
  float e = __expf(s - m);
  float sum = e;
  for (int off = 4; off; off >>= 1) sum += __shfl_xor(sum, off, 8);
  attn[t] = e / sum;
}

// ---------------- dynamic bias ----------------
__global__ void k_bdyn(const float* __restrict__ attn, const float* __restrict__ expert_b,
                       float* __restrict__ bdyn) {
  int j = blockIdx.x * 256 + threadIdx.x;
  if (j >= B_ * CO) return;
  int b = j / CO, o = j - b * CO;
  float s = 0.f;
  #pragma unroll
  for (int e = 0; e < KE; ++e) s += attn[b*KE + e] * expert_b[e*CO + o];
  bdyn[j] = s;
}

// ---------------- dynamic weights -> staged layout [b][kt=54][chunk=12][slot=64][8] bf16
// K order: kt = r*18 + ib*3 + s  (s innermost). slot L holds (row=L>>2, ks=(L&3)^((row>>1)&3)).
// element: o = chunk*16+row, i = ib*32 + ks*8 + j, weight (o, i, r, s).
__global__ void k_wdyn(const float* __restrict__ expert_w, const float* __restrict__ attn,
                       bf16* __restrict__ w_re) {
  int o = blockIdx.x;            // 192
  int chunk = o >> 4, row = o & 15, c = (row >> 1) & 3;
  __shared__ float ew[KE][KTOT];
  __shared__ float al[B_][KE];
  for (int e = 0; e < KE; ++e)
    for (int j = threadIdx.x; j < KTOT; j += 256)
      ew[e][j] = expert_w[((size_t)e*CO + o)*KTOT + j];   // [i*9+rs]
  if (threadIdx.x < B_*KE) al[threadIdx.x >> 3][threadIdx.x & 7] = attn[threadIdx.x];
  __syncthreads();
  for (int idx = threadIdx.x; idx < B_*KTOT; idx += 256) {
    int b = idx / KTOT, k = idx - b*KTOT;
    int kt = k >> 5, ks = (k >> 3) & 3, j = k & 7;
    int r = kt / 18, t2 = kt - r*18;
    int ibb = t2 / 3, s = t2 - ibb*3;
    int i = ibb*32 + ks*8 + j;
    float acc = 0.f;
    #pragma unroll
    for (int e = 0; e < KE; ++e) acc += al[b][e] * ew[e][i*9 + r*3 + s];
    int slot = row*4 + (ks ^ c);
    w_re[((((size_t)b*NT + kt)*12 + chunk)*64 + slot)*8 + j] = (bf16)acc;
  }
}

// ---------------- static conv2 weights -> same staged layout (no b) ----------------
__global__ void k_w2re(const float* __restrict__ conv2_w, bf16* __restrict__ w2_re) {
  int o = blockIdx.x;
  int chunk = o >> 4, row = o & 15, c = (row >> 1) & 3;
  __shared__ float cw[KTOT];
  for (int j = threadIdx.x; j < KTOT; j += 256) cw[j] = conv2_w[(size_t)o*KTOT + j];
  __syncthreads();
  for (int k = threadIdx.x; k < KTOT; k += 256) {
    int kt = k >> 5, ks = (k >> 3) & 3, j = k & 7;
    int r = kt / 18, t2 = kt - r*18;
    int ibb = t2 / 3, s = t2 - ibb*3;
    int i = ibb*32 + ks*8 + j;
    int slot = row*4 + (ks ^ c);
    w2_re[(((size_t)kt*12 + chunk)*64 + slot)*8 + j] = (bf16)cw[i*9 + r*3 + s];
  }
}

// ---------------- pack+pad x: f32 NCHW -> bf16 [b][i/8][130][130][8], zero borders ----------------
__global__ void k_xpack(const float* __restrict__ x, bf16* __restrict__ xpack) {
  int h2 = blockIdx.x, ib = blockIdx.y, b = blockIdx.z;
  size_t rowbase = (((size_t)b*24 + ib)*HP + h2)*HP;
  int t = threadIdx.x;  // 128
  if (h2 == 0 || h2 == HP-1) {
    uint4 z = make_uint4(0,0,0,0);
    for (int w = t; w < HP; w += 128) *(uint4*)(xpack + (rowbase + w)*8) = z;
    return;
  }
  __shared__ float tt[8][128];
  int h = h2 - 1;
  #pragma unroll
  for (int ii = 0; ii < 8; ++ii)
    tt[ii][t] = x[(((size_t)b*CI + ib*8 + ii)*H_ + h)*W_ + t];
  __syncthreads();
  bf16x8 v;
  #pragma unroll
  for (int ii = 0; ii < 8; ++ii) v[ii] = (bf16)tt[ii][t];
  *(bf16x8*)(xpack + (rowbase + t + 1)*8) = v;
  if (t == 0) {
    uint4 z = make_uint4(0,0,0,0);
    *(uint4*)(xpack + rowbase*8) = z;
    *(uint4*)(xpack + (rowbase + HP-1)*8) = z;
  }
}

// ---------------- zero borders of midpack ----------------
__global__ void k_midborder(bf16* __restrict__ midpack) {
  int bi = blockIdx.x;  // b*24+ib
  size_t base = (size_t)bi * HPHP;
  uint4 z = make_uint4(0,0,0,0);
  for (int j = threadIdx.x; j < 516; j += 256) {
    int h2, w2;
    if (j < 130)      { h2 = 0;       w2 = j; }
    else if (j < 260) { h2 = 129;     w2 = j - 130; }
    else if (j < 388) { h2 = j - 259; w2 = 0; }
    else              { h2 = j - 387; w2 = 129; }
    *(uint4*)(midpack + (base + (size_t)h2*HP + w2)*8) = z;
  }
}

// ---------------- implicit-GEMM 3x3 conv, BM=192 x BN=256(2 rows), K order (r,ib,s) ----------------
// R5 pipeline (proven 232us) + T3 2-phase micro split (counted-vmcnt preserved):
// 4 waves (2m x 2n), per-wave 96x128. 18 macros (r,ib) x 3 micros (s).
// B staged once per macro; s served by +16B shift on the LDS read. A triple-buffered
// (lead 2 micros, buf = s), B double-buffered (lead 3 micros).
// Per micro: entry vmcnt(3)/(3)/(8) + barrier;
//   P1: ds_read af0-5,bv0-3 ; issue A(u+2) ; BAR ; prio1 24 MFMA(nf0-3) prio0
//   P2: ds_read bv4-7       ; issue B(m+1) on s1 ; BAR ; prio1 24 MFMA(nf4-7) prio0
template<int MODE>
__global__ __launch_bounds__(256, 2)
void k_conv(const bf16* __restrict__ wre, const bf16* __restrict__ inpack,
            const float* __restrict__ bias_g, const bf16* __restrict__ respack,
            bf16* __restrict__ outpack, float* __restrict__ outp) {
  const int tid  = threadIdx.x;
  const int lane = tid & 63;
  const int wv   = tid >> 6;          // 0..3
  const int wm   = wv >> 1;           // 0..1 (o half)
  const int wn   = wv & 1;            // 0..1 (p half = image row)
  const int l15  = lane & 15, l4 = lane >> 4;

  // XCD-aware chunked remap: 1024 blocks, 128/XCD => each XCD owns 2 batches
  const int bid  = blockIdx.x;
  const int n    = (bid & 7) * 128 + (bid >> 3);
  const int b    = n >> 6;
  const int tile = n & 63;
  const int p0   = tile * 256;
  const int h0   = tile * 2;

  __shared__ __align__(16) bf16 Alds[3][12*512];    // 36864 B
  __shared__ __align__(16) bf16 Blds[2][4*2560];    // 40960 B
  __shared__ float bias_lds[CO];

  if (tid < CO) bias_lds[tid] = (MODE == 0) ? bias_g[b*CO + tid] : bias_g[tid];

  const size_t wbase = (MODE == 0) ? ((size_t)b*CO*KTOT) : 0;

  // A staging: 12 chunks of 1KB per micro-step; wave wv stages {wv, wv+4, wv+8}
  const bf16* aS = wre + wbase + (size_t)wv*512 + lane*8;
  // B staging: wave wv stages kg=wv; 5 overlapped chunks over contiguous row-pair (4160B)
  const bf16* bbase = inpack + (((size_t)b*24 + wv)*HPHP + (size_t)h0*HP)*8 + lane*8;
  int ibm = 0; ptrdiff_t boffEl = 0;   // macro (r,ib) element offset

  auto stageA = [&](bf16* dbuf) {
    bf16* d = dbuf + wv*512;
    gll16(aS,        d);
    gll16(aS + 2048, d + 2048);
    gll16(aS + 4096, d + 4096);
    aS += 6144;
  };
  auto stageB = [&](bf16* dbuf) {
    const bf16* src = bbase + boffEl;
    bf16* d = dbuf + wv*2560;
    gll16(src,        d);
    gll16(src +  512, d +  512);
    gll16(src + 1024, d + 1024);
    gll16(src + 1536, d + 1536);
    gll16(src + 1568, d + 1568);   // overlapped tail chunk (3136..4159 B)
    if (++ibm == 6) { ibm = 0; boffEl += (ptrdiff_t)(HP - 20*HPHP)*8; }
    else boffEl += (ptrdiff_t)4*HPHP*8;
  };

  f32x4 acc[6][8];
  #pragma unroll
  for (int mf = 0; mf < 6; ++mf)
    #pragma unroll
    for (int nf = 0; nf < 8; ++nf)
      #pragma unroll
      for (int jj = 0; jj < 4; ++jj) acc[mf][nf][jj] = 0.f;

  const int sw = l15*4 + (l4 ^ ((l15 >> 1) & 3));       // swizzled A slot
  const int bvb = l4*2560 + (wn*130 + l15)*8;           // B read base (elements)

  // prologue: A(0), A(1), B(0)
  stageA(Alds[0]);
  stageA(Alds[1]);
  stageB(Blds[0]);

  bf16* Bcur = (bf16*)Blds[0];
  bf16* Bnxt = (bf16*)Blds[1];

  for (int m = 0; m < 18; ++m) {
    #pragma unroll
    for (int s = 0; s < 3; ++s) {
      // ---- entry wait + barrier (same counted schedule as R5) ----
      if (s == 2) {
        if (m == 17) asm volatile("s_waitcnt vmcnt(0)" ::: "memory");
        else         asm volatile("s_waitcnt vmcnt(8)" ::: "memory");
      } else {
        asm volatile("s_waitcnt vmcnt(3)" ::: "memory");
      }
      __builtin_amdgcn_s_barrier();

      const bf16* A = Alds[s];          // u%3 == s
      const bf16* bp = Bcur + bvb + s*8;

      // ---- P1: reads + A-stage, then 24 MFMA (nf 0-3) ----
      bf16x8 af0 = *(const bf16x8*)(A + (wm*6 + 0)*512 + sw*8);
      bf16x8 af1 = *(const bf16x8*)(A + (wm*6 + 1)*512 + sw*8);
      bf16x8 af2 = *(const bf16x8*)(A + (wm*6 + 2)*512 + sw*8);
      bf16x8 af3 = *(const bf16x8*)(A + (wm*6 + 3)*512 + sw*8);
      bf16x8 af4 = *(const bf16x8*)(A + (wm*6 + 4)*512 + sw*8);
      bf16x8 af5 = *(const bf16x8*)(A + (wm*6 + 5)*512 + sw*8);
      bf16x8 bv0 = *(const bf16x8*)(bp);
      bf16x8 bv1 = *(const bf16x8*)(bp + 128);
      bf16x8 bv2 = *(const bf16x8*)(bp + 256);
      bf16x8 bv3 = *(const bf16x8*)(bp + 384);

      if (3*m + s + 2 < NT) stageA(Alds[(s+2)%3]);     // A(u+2)

      __builtin_amdgcn_s_barrier();
      __builtin_amdgcn_s_setprio(1);
      acc[0][0] = __builtin_amdgcn_mfma_f32_16x16x32_bf16(af0, bv0, acc[0][0], 0, 0, 0);
      acc[1][0] = __builtin_amdgcn_mfma_f32_16x16x32_bf16(af1, bv0, acc[1][0], 0, 0, 0);
      acc[2][0] = __builtin_amdgcn_mfma_f32_16x16x32_bf16(af2, bv0, acc[2][0], 0, 0, 0);
      acc[3][0] = __builtin_amdgcn_mfma_f32_16x16x32_bf16(af3, bv0, acc[3][0], 0, 0, 0);
      acc[4][0] = __builtin_amdgcn_mfma_f32_16x16x32_bf16(af4, bv0, acc[4][0], 0, 0, 0);
      acc[5][0] = __builtin_amdgcn_mfma_f32_16x16x32_bf16(af5, bv0, acc[5][0], 0, 0, 0);
      acc[0][1] = __builtin_amdgcn_mfma_f32_16x16x32_bf16(af0, bv1, acc[0][1], 0, 0, 0);
      acc[1][1] = __builtin_amdgcn_mfma_f32_16x16x32_bf16(af1, bv1, acc[1][1], 0, 0, 0);
      acc[2][1] = __builtin_amdgcn_mfma_f32_16x16x32_bf16(af2, bv1, acc[2][1], 0, 0, 0);
      acc[3][1] = __builtin_amdgcn_mfma_f32_16x16x32_bf16(af3, bv1, acc[3][1], 0, 0, 0);
      acc[4][1] = __builtin_amdgcn_mfma_f32_16x16x32_bf16(af4, bv1, acc[4][1], 0, 0, 0);
      acc[5][1] = __builtin_amdgcn_mfma_f32_16x16x32_bf16(af5, bv1, acc[5][1], 0, 0, 0);
      acc[0][2] = __builtin_amdgcn_mfma_f32_16x16x32_bf16(af0, bv2, acc[0][2], 0, 0, 0);
      acc[1][2] = __builtin_amdgcn_mfma_f32_16x16x32_bf16(af1, bv2, acc[1][2], 0, 0, 0);
      acc[2][2] = __builtin_amdgcn_mfma_f32_16x16x32_bf16(af2, bv2, acc[2][2], 0, 0, 0);
      acc[3][2] = __builtin_amdgcn_mfma_f32_16x16x32_bf16(af3, bv2, acc[3][2], 0, 0, 0);
      acc[4][2] = __builtin_amdgcn_mfma_f32_16x16x32_bf16(af4, bv2, acc[4][2], 0, 0, 0);
      acc[5][2] = __builtin_amdgcn_mfma_f32_16x16x32_bf16(af5, bv2, acc[5][2], 0, 0, 0);
      acc[0][3] = __builtin_amdgcn_mfma_f32_16x16x32_bf16(af0, bv3, acc[0][3], 0, 0, 0);
      acc[1][3] = __builtin_amdgcn_mfma_f32_16x16x32_bf16(af1, bv3, acc[1][3], 0, 0, 0);
      acc[2][3] = __builtin_amdgcn_mfma_f32_16x16x32_bf16(af2, bv3, acc[2][3], 0, 0, 0);
      acc[3][3] = __builtin_amdgcn_mfma_f32_16x16x32_bf16(af3, bv3, acc[3][3], 0, 0, 0);
      acc[4][3] = __builtin_amdgcn_mfma_f32_16x16x32_bf16(af4, bv3, acc[4][3], 0, 0, 0);
      acc[5][3] = __builtin_amdgcn_mfma_f32_16x16x32_bf16(af5, bv3, acc[5][3], 0, 0, 0);
      __builtin_amdgcn_s_setprio(0);

      // ---- P2: reads + B-stage, then 24 MFMA (nf 4-7) ----
      bf16x8 bv4 = *(const bf16x8*)(bp + 512);
      bf16x8 bv5 = *(const bf16x8*)(bp + 640);
      bf16x8 bv6 = *(const bf16x8*)(bp + 768);
      bf16x8 bv7 = *(const bf16x8*)(bp + 896);

      if (s == 1 && m < 17) stageB(Bnxt);              // B(m+1)

      __builtin_amdgcn_s_barrier();
      __builtin_amdgcn_s_setprio(1);
      acc[0][4] = __builtin_amdgcn_mfma_f32_16x16x32_bf16(af0, bv4, acc[0][4], 0, 0, 0);
      acc[1][4] = __builtin_amdgcn_mfma_f32_16x16x32_bf16(af1, bv4, acc[1][4], 0, 0, 0);
      acc[2][4] = __builtin_amdgcn_mfma_f32_16x16x32_bf16(af2, bv4, acc[2][4], 0, 0, 0);
      acc[3][4] = __builtin_amdgcn_mfma_f32_16x16x32_bf16(af3, bv4, acc[3][4], 0, 0, 0);
      acc[4][4] = __builtin_amdgcn_mfma_f32_16x16x32_bf16(af4, bv4, acc[4][4], 0, 0, 0);
      acc[5][4] = __builtin_amdgcn_mfma_f32_16x16x32_bf16(af5, bv4, acc[5][4], 0, 0, 0);
      acc[0][5] = __builtin_amdgcn_mfma_f32_16x16x32_bf16(af0, bv5, acc[0][5], 0, 0, 0);
      acc[1][5] = __builtin_amdgcn_mfma_f32_16x16x32_bf16(af1, bv5, acc[1][5], 0, 0, 0);
      acc[2][5] = __builtin_amdgcn_mfma_f32_16x16x32_bf16(af2, bv5, acc[2][5], 0, 0, 0);
      acc[3][5] = __builtin_amdgcn_mfma_f32_16x16x32_bf16(af3, bv5, acc[3][5], 0, 0, 0);
      acc[4][5] = __builtin_amdgcn_mfma_f32_16x16x32_bf16(af4, bv5, acc[4][5], 0, 0, 0);
      acc[5][5] = __builtin_amdgcn_mfma_f32_16x16x32_bf16(af5, bv5, acc[5][5], 0, 0, 0);
      acc[0][6] = __builtin_amdgcn_mfma_f32_16x16x32_bf16(af0, bv6, acc[0][6], 0, 0, 0);
      acc[1][6] = __builtin_amdgcn_mfma_f32_16x16x32_bf16(af1, bv6, acc[1][6], 0, 0, 0);
      acc[2][6] = __builtin_amdgcn_mfma_f32_16x16x32_bf16(af2, bv6, acc[2][6], 0, 0, 0);
      acc[3][6] = __builtin_amdgcn_mfma_f32_16x16x32_bf16(af3, bv6, acc[3][6], 0, 0, 0);
      acc[4][6] = __builtin_amdgcn_mfma_f32_16x16x32_bf16(af4, bv6, acc[4][6], 0, 0, 0);
      acc[5][6] = __builtin_amdgcn_mfma_f32_16x16x32_bf16(af5, bv6, acc[5][6], 0, 0, 0);
      acc[0][7] = __builtin_amdgcn_mfma_f32_16x16x32_bf16(af0, bv7, acc[0][7], 0, 0, 0);
      acc[1][7] = __builtin_amdgcn_mfma_f32_16x16x32_bf16(af1, bv7, acc[1][7], 0, 0, 0);
      acc[2][7] = __builtin_amdgcn_mfma_f32_16x16x32_bf16(af2, bv7, acc[2][7], 0, 0, 0);
      acc[3][7] = __builtin_amdgcn_mfma_f32_16x16x32_bf16(af3, bv7, acc[3][7], 0, 0, 0);
      acc[4][7] = __builtin_amdgcn_mfma_f32_16x16x32_bf16(af4, bv7, acc[4][7], 0, 0, 0);
      acc[5][7] = __builtin_amdgcn_mfma_f32_16x16x32_bf16(af5, bv7, acc[5][7], 0, 0, 0);
      __builtin_amdgcn_s_setprio(0);
    }
    { bf16* t = Bcur; Bcur = Bnxt; Bnxt = t; }
  }

  // epilogue
  #pragma unroll
  for (int mf = 0; mf < 6; ++mf) {
    int ob = wm*96 + mf*16 + l4*4;     // output channel base (4 consecutive)
    #pragma unroll
    for (int nf = 0; nf < 8; ++nf) {
      int pl = wn*128 + nf*16 + l15;
      int p  = p0 + pl;
      f32x4 v = acc[mf][nf];
      int h = p >> 7, w = p & 127;
      size_t basep = (((size_t)b*24 + (ob >> 3))*HP + (h + 1))*HP + (w + 1);
      if (MODE == 0) {
        bf16x4 pk;
        #pragma unroll
        for (int jj = 0; jj < 4; ++jj) {
          float xv = v[jj] + bias_lds[ob + jj];
          pk[jj] = (bf16)silu_f(xv);
        }
        *(bf16x4*)(outpack + basep*8 + (ob & 7)) = pk;
      } else {
        bf16x4 rr = *(const bf16x4*)(respack + basep*8 + (ob & 7));
        #pragma unroll
        for (int jj = 0; jj < 4; ++jj) {
          float xv = silu_f(v[jj] + bias_lds[ob + jj]);
          size_t idx = ((size_t)b*CO + ob + jj)*NPX + p;
          outp[idx] = xv + (float)rr[jj];
        }
      }
    }
  }
}

extern "C" void kernel_launch(void* const* d_in, const int* in_sizes, int n_in,
                              void* d_out, int out_size, void* d_ws, size_t ws_size,
                              hipStream_t stream) {
  const float* x        = (const float*)d_in[0];
  const float* latent   = (const float*)d_in[1];
  const float* expert_w = (const float*)d_in[2];
  const float* expert_b = (const float*)d_in[3];
  const float* attn_w   = (const float*)d_in[4];
  const float* attn_b   = (const float*)d_in[5];
  const float* conv2_w  = (const float*)d_in[6];
  const float* conv2_b  = (const float*)d_in[7];
  float* outp = (float*)d_out;

  char* base = (char*)d_ws;
  size_t off = 0;
  float* attn = (float*)(base + off); off += 4096;
  float* bdyn = (float*)(base + off); off += 16384;
  bf16* w_re  = (bf16*)(base + off);  off += (size_t)B_*CO*KTOT*2;      // 10.6 MB
  bf16* w2_re = (bf16*)(base + off);  off += (size_t)CO*KTOT*2;         // 0.66 MB
  bf16* xpack = (bf16*)(base + off);  off += (size_t)B_*24*HPHP*8*2;    // 103.8 MB
  bf16* midpack = (bf16*)(base + off); off += (size_t)B_*24*HPHP*8*2;   // 103.8 MB
  (void)ws_size; (void)in_sizes; (void)n_in; (void)out_size;

  k_attn<<<dim3(1), dim3(128), 0, stream>>>(latent, attn_w, attn_b, attn);
  k_bdyn<<<dim3(12), dim3(256), 0, stream>>>(attn, expert_b, bdyn);
  k_wdyn<<<dim3(CO), dim3(256), 0, stream>>>(expert_w, attn, w_re);
  k_w2re<<<dim3(CO), dim3(256), 0, stream>>>(conv2_w, w2_re);
  k_xpack<<<dim3(130, 24, 16), dim3(128), 0, stream>>>(x, xpack);
  k_midborder<<<dim3(B_*24), dim3(256), 0, stream>>>(midpack);
  k_conv<0><<<dim3(1024), dim3(256), 0, stream>>>(w_re, xpack, bdyn, xpack, midpack, outp);
  k_conv<1><<<dim3(1024), dim3(256), 0, stream>>>(w2_re, midpack, conv2_b, xpack, midpack, outp);
}